// Round 4
// baseline (128.058 us; speedup 1.0000x reference)
//
#include <hip/hip_runtime.h>
#include <math.h>

// EdgeConv: B=16, N=8192, K=20, D=64
// h[b,n,k,o] = Y1[b,idx,o] + Bs[b,n,o];  out = GELU(LN(max_k h))
// Y1[p][o] = sum_d x[p][d]*W[o][d]          (bf16 table, gathered)
// Bs[p][o] = sum_d x[p][d]*(W[o][64+d]-W[o][d])   (bf16, streamed)
// 2-kernel pipeline: prep folded into proj's LDS staging (W is 32KB, L2-hot).
#define B_ 16
#define N_ 8192
#define K_ 20
#define NPTS (B_ * N_)   // 131072

typedef __attribute__((ext_vector_type(4))) float f4;
typedef __attribute__((ext_vector_type(8))) short s8;          // 8 x bf16 MFMA fragment
typedef __attribute__((ext_vector_type(4))) unsigned int u4;   // 16B untyped
typedef __attribute__((ext_vector_type(4))) unsigned short us4;// 8B packed bf16

__device__ __forceinline__ unsigned short f2bf(float f) {
    union { float f; unsigned u; } v; v.f = f;
    return (unsigned short)((v.u + 0x7FFFu + ((v.u >> 16) & 1u)) >> 16);   // RNE
}
__device__ __forceinline__ float bfhi(unsigned w) { return __uint_as_float(w & 0xFFFF0000u); }
__device__ __forceinline__ float bflo(unsigned w) { return __uint_as_float(w << 16); }
__device__ __forceinline__ float max3f(float a, float b, float c) {
    float d;
    asm("v_max3_f32 %0, %1, %2, %3" : "=v"(d) : "v"(a), "v"(b), "v"(c));
    return d;
}

// ---------------- Kernel 1: projections via MFMA (A=W, B=x) ----------------
// W staging folded in: combined Wg rows (0..63 = W[:,d]; 64..127 =
// W[:,64+d]-W[:,d]) built from L2-resident W straight into LDS, same
// 4-iter/thread 16B-chunk pattern as the proven Wg staging loop.
// Each wave: 16 points x 128 outputs. D-layout: row(o-in-tile)=q*4+j, col(point)=m.
// => lane's 4 acc regs are 4 CONSECUTIVE output channels -> packed 8B stores.
__global__ __launch_bounds__(256) void proj_kernel(const float* __restrict__ x,
                                                   const float* __restrict__ W,
                                                   unsigned short* __restrict__ Y1,
                                                   unsigned short* __restrict__ Bs) {
    __shared__ unsigned short Wl[128 * 72];   // row stride 144B: 2-way bank alias = free
    const int t = threadIdx.x;

    // 1024 chunks of 8 bf16 (16B LDS each); j<64 uniform for iters 0-1, >=64 for 2-3.
    for (int i = t; i < 1024; i += 256) {
        const int j = i >> 3, d0 = (i & 7) * 8;
        f4 v0, v1;
        if (j < 64) {
            v0 = *(const f4*)&W[j * 128 + d0];
            v1 = *(const f4*)&W[j * 128 + d0 + 4];
        } else {
            const int r = j - 64;
            f4 a0 = *(const f4*)&W[r * 128 + 64 + d0];
            f4 a1 = *(const f4*)&W[r * 128 + 64 + d0 + 4];
            f4 c0 = *(const f4*)&W[r * 128 + d0];
            f4 c1 = *(const f4*)&W[r * 128 + d0 + 4];
            v0 = a0 - c0; v1 = a1 - c1;
        }
        us4 u0, u1;
        u0.x = f2bf(v0.x); u0.y = f2bf(v0.y); u0.z = f2bf(v0.z); u0.w = f2bf(v0.w);
        u1.x = f2bf(v1.x); u1.y = f2bf(v1.y); u1.z = f2bf(v1.z); u1.w = f2bf(v1.w);
        char* dst = (char*)Wl + j * 144 + d0 * 2;
        *(us4*)dst = u0;
        *(us4*)(dst + 8) = u1;
    }
    __syncthreads();

    const int lane = t & 63;
    const int wv = t >> 6;
    const int m = lane & 15;          // point-within-tile (B idx) AND W-row-within-tile (A idx)
    const int q = lane >> 4;
    const int pbase = blockIdx.x * 64 + wv * 16;

    // B-frag (x): lane reads 16B-contig chunks of its point's row
    const float* xr = x + (size_t)(pbase + m) * 64 + q * 8;
    f4 x0 = *(const f4*)(xr);
    f4 x1 = *(const f4*)(xr + 4);
    f4 x2 = *(const f4*)(xr + 32);
    f4 x3 = *(const f4*)(xr + 36);
    s8 X0, X1;
    X0[0]=(short)f2bf(x0.x); X0[1]=(short)f2bf(x0.y); X0[2]=(short)f2bf(x0.z); X0[3]=(short)f2bf(x0.w);
    X0[4]=(short)f2bf(x1.x); X0[5]=(short)f2bf(x1.y); X0[6]=(short)f2bf(x1.z); X0[7]=(short)f2bf(x1.w);
    X1[0]=(short)f2bf(x2.x); X1[1]=(short)f2bf(x2.y); X1[2]=(short)f2bf(x2.z); X1[3]=(short)f2bf(x2.w);
    X1[4]=(short)f2bf(x3.x); X1[5]=(short)f2bf(x3.y); X1[6]=(short)f2bf(x3.z); X1[7]=(short)f2bf(x3.w);

    f4 acc[8];
#pragma unroll
    for (int tt = 0; tt < 8; ++tt) acc[tt] = (f4)0.f;

#pragma unroll
    for (int s = 0; s < 2; ++s) {
        const s8 X = s ? X1 : X0;
#pragma unroll
        for (int tt = 0; tt < 8; ++tt) {
            // A-frag (W): A[m][k=s*32+q*8+j], 16B-aligned in padded LDS
            s8 w = *(const s8*)((const char*)Wl + (16 * tt + m) * 144 + s * 64 + q * 16);
            acc[tt] = __builtin_amdgcn_mfma_f32_16x16x32_bf16(w, X, acc[tt], 0, 0, 0);
        }
    }

    // D: o = 16*tt + q*4 + j, point = pbase + m  -> packed us4 (8B) stores
    const size_t prow = (size_t)(pbase + m) * 64;
#pragma unroll
    for (int tt = 0; tt < 4; ++tt) {
        us4 u;
        u.x = f2bf(acc[tt][0]); u.y = f2bf(acc[tt][1]);
        u.z = f2bf(acc[tt][2]); u.w = f2bf(acc[tt][3]);
        *(us4*)&Y1[prow + tt * 16 + q * 4] = u;
    }
#pragma unroll
    for (int tt = 4; tt < 8; ++tt) {
        us4 u;
        u.x = f2bf(acc[tt][0]); u.y = f2bf(acc[tt][1]);
        u.z = f2bf(acc[tt][2]); u.w = f2bf(acc[tt][3]);
        *(us4*)&Bs[prow + (tt - 4) * 16 + q * 4] = u;
    }
}

// ---------------- Kernel 2: gather + max + LN + GELU ----------------
// 8 points/wave, 8 lanes/point, 8 ch/lane: 16B gathers (half the VMEM instrs).
// XCD mapping: sequential-batch-per-XCD (r3): xcd=bi&7, one 2.1MB table per
// XCD at a time. v_max3_f32 halves the max-chain VALU count (proven exact).
__global__ __launch_bounds__(256) void gather_kernel(const unsigned short* __restrict__ Y1,
                                                     const unsigned short* __restrict__ Bs,
                                                     const int* __restrict__ ind,
                                                     const float* __restrict__ gamma,
                                                     const float* __restrict__ beta,
                                                     float* __restrict__ out) {
    const int lane = threadIdx.x & 63;
    const int wave = threadIdx.x >> 6;
    const int sub = lane & 7;            // channel group (8 ch)
    const int q = lane >> 3;             // point within wave
    const int bi = blockIdx.x;           // 4096 blocks
    const int xcd = bi & 7;
    const int s2 = bi >> 3;              // 0..511
    const int bt = xcd + 8 * (s2 >> 8);  // batch: one table per XCD at a time
    const int jj = s2 & 255;             // 256 blocks per batch
    const int p = bt * N_ + jj * 32 + wave * 8 + q;
    const int bbase = bt * N_ * 64;

    int idxs[K_];
    const int4* ip = (const int4*)&ind[p * K_];   // 80B/point, 16B-aligned
#pragma unroll
    for (int v = 0; v < 5; ++v) {
        int4 iv = ip[v];
        idxs[4 * v + 0] = iv.x; idxs[4 * v + 1] = iv.y;
        idxs[4 * v + 2] = iv.z; idxs[4 * v + 3] = iv.w;
    }

    f4 ma = (f4)(-INFINITY), mb = (f4)(-INFINITY);
#pragma unroll
    for (int r = 0; r < 2; ++r) {        // 2 rounds x 10 outstanding 16B gathers
        u4 rv[10];
#pragma unroll
        for (int k = 0; k < 10; ++k)
            rv[k] = *(const u4*)(Y1 + bbase + idxs[r * 10 + k] * 64 + sub * 8);
#pragma unroll
        for (int k = 0; k < 10; k += 2) {
            u4 a = rv[k], c = rv[k + 1];
            ma.x = max3f(ma.x, bflo(a.x), bflo(c.x));
            ma.y = max3f(ma.y, bfhi(a.x), bfhi(c.x));
            ma.z = max3f(ma.z, bflo(a.y), bflo(c.y));
            ma.w = max3f(ma.w, bfhi(a.y), bfhi(c.y));
            mb.x = max3f(mb.x, bflo(a.z), bflo(c.z));
            mb.y = max3f(mb.y, bfhi(a.z), bfhi(c.z));
            mb.z = max3f(mb.z, bflo(a.w), bflo(c.w));
            mb.w = max3f(mb.w, bfhi(a.w), bfhi(c.w));
        }
    }

    u4 bsv = __builtin_nontemporal_load((const u4*)(Bs + (size_t)p * 64 + sub * 8));
    f4 ha, hb;
    ha.x = ma.x + bflo(bsv.x); ha.y = ma.y + bfhi(bsv.x);
    ha.z = ma.z + bflo(bsv.y); ha.w = ma.w + bfhi(bsv.y);
    hb.x = mb.x + bflo(bsv.z); hb.y = mb.y + bfhi(bsv.z);
    hb.z = mb.z + bflo(bsv.w); hb.w = mb.w + bfhi(bsv.w);

    // LayerNorm over 64 ch = 8 comps x 8 lanes (xor masks 1,2,4 stay in-group)
    float s = ha.x + ha.y + ha.z + ha.w + hb.x + hb.y + hb.z + hb.w;
#pragma unroll
    for (int off = 4; off >= 1; off >>= 1) s += __shfl_xor(s, off, 64);
    const float mu = s * (1.0f / 64.0f);
    f4 da = ha - mu, db = hb - mu;
    float v2 = da.x * da.x + da.y * da.y + da.z * da.z + da.w * da.w
             + db.x * db.x + db.y * db.y + db.z * db.z + db.w * db.w;
#pragma unroll
    for (int off = 4; off >= 1; off >>= 1) v2 += __shfl_xor(v2, off, 64);
    const float rstd = rsqrtf(v2 * (1.0f / 64.0f) + 1e-5f);

    const f4 g0 = *(const f4*)&gamma[sub * 8];
    const f4 g1 = *(const f4*)&gamma[sub * 8 + 4];
    const f4 b0 = *(const f4*)&beta[sub * 8];
    const f4 b1 = *(const f4*)&beta[sub * 8 + 4];
    f4 na = da * rstd * g0 + b0;
    f4 nb = db * rstd * g1 + b1;

    f4 r0, r1;
    r0.x = 0.5f * na.x * (1.0f + erff(na.x * 0.70710678f));
    r0.y = 0.5f * na.y * (1.0f + erff(na.y * 0.70710678f));
    r0.z = 0.5f * na.z * (1.0f + erff(na.z * 0.70710678f));
    r0.w = 0.5f * na.w * (1.0f + erff(na.w * 0.70710678f));
    r1.x = 0.5f * nb.x * (1.0f + erff(nb.x * 0.70710678f));
    r1.y = 0.5f * nb.y * (1.0f + erff(nb.y * 0.70710678f));
    r1.z = 0.5f * nb.z * (1.0f + erff(nb.z * 0.70710678f));
    r1.w = 0.5f * nb.w * (1.0f + erff(nb.w * 0.70710678f));
    float* op = &out[(size_t)p * 64 + sub * 8];
    __builtin_nontemporal_store(r0, (f4*)op);
    __builtin_nontemporal_store(r1, (f4*)(op + 4));
}

extern "C" void kernel_launch(void* const* d_in, const int* in_sizes, int n_in,
                              void* d_out, int out_size, void* d_ws, size_t ws_size,
                              hipStream_t stream) {
    const float* x     = (const float*)d_in[0];
    const int*   ind   = (const int*)d_in[1];
    const float* W     = (const float*)d_in[2];
    const float* gamma = (const float*)d_in[3];
    const float* beta  = (const float*)d_in[4];
    float* out = (float*)d_out;

    unsigned short* Bs = (unsigned short*)d_ws;          // 16.8 MB bf16
    unsigned short* Y1 = Bs + (size_t)NPTS * 64;         // 16.8 MB bf16

    proj_kernel<<<NPTS / 64, 256, 0, stream>>>(x, W, Y1, Bs);
    gather_kernel<<<NPTS / 32, 256, 0, stream>>>(Y1, Bs, ind, gamma, beta, out);
}